// Round 16
// baseline (35.367 us; speedup 1.0000x reference)
//
#include <hip/hip_runtime.h>
#include <hip/hip_bf16.h>

// Problem constants (fixed by reference)
#define NB   32      // N  (batch)
#define CIN  32      // INC
#define COUT 32      // OUTC
#define INN_ 16384   // INN
#define ON   4096    // OUTN
#define MD   16      // MAXD

typedef __attribute__((ext_vector_type(8))) short bf16x8;  // 8 bf16 = 4 VGPR
typedef __attribute__((ext_vector_type(4))) float f32x4;

typedef const __attribute__((address_space(1))) void* gas_ptr;
typedef __attribute__((address_space(3))) void* las_ptr;

// ---------------------------------------------------------------------------
// Kernel 1: premix via MFMA, async global_load_lds staging (R15), with
// XCD-ALIGNED block mapping: xcd = L&7 owns n in [4*xcd, 4*xcd+4) — the SAME
// n->XCD mapping as the gather kernel, so zT[n] (1MB x 4 = 4MB) is produced
// into and consumed from the same per-XCD L2.
//   zT[n][j][c] = sum_i x[n][i][j] * w[i][c]   (bf16, layout [n][j][c])
// Grid: 4096 blocks x 256 thr (4 waves x 2 subtiles), LDS 16KB, 8 blocks/CU.
// ---------------------------------------------------------------------------
__global__ __launch_bounds__(256) void premix_mfma_kernel(
    const float* __restrict__ x,
    const float* __restrict__ weight,
    unsigned short* __restrict__ zT) {
  __shared__ float xs[CIN * 128];  // linear, 16 KB

  const int tid  = threadIdx.x;
  const int lane = tid & 63;
  const int wv   = tid >> 6;
  const int l15  = lane & 15;
  const int grp  = lane >> 4;   // 0..3
  const int kq0  = grp << 3;    // i-base 0,8,16,24

  // XCD-aligned mapping (matches gather): L&7 -> xcd; 512 slots per xcd.
  const int L    = blockIdx.x;
  const int xcd  = L & 7;
  const int slot = L >> 3;                  // 0..511
  const int n    = xcd * 4 + (slot >> 7);   // 4 n per xcd
  const int j0   = (slot & 127) << 7;       // 128-j tile

  // ---- issue async stage FIRST: chunk c = r*4 + wv covers rows 2c,2c+1.
  // lane -> row = 2c + (lane>>5); global col = ((lane&31)*4) ^ ((row&24)<<1).
  const float* xgbase = x + (((size_t)n * CIN) << 14) + j0;
#pragma unroll
  for (int r = 0; r < 4; ++r) {
    const int c   = (r << 2) + wv;
    const int row = (c << 1) + (lane >> 5);
    const int off = ((lane & 31) << 2) ^ ((row & 24) << 1);
    const float* gsrc = xgbase + ((size_t)row << 14) + off;
    __builtin_amdgcn_global_load_lds((gas_ptr)(const void*)gsrc,
                                     (las_ptr)(void*)&xs[c << 8], 16, 0, 0);
  }

  // ---- weight fragments (loop-invariant, hi/lo split) — hides DMA latency.
  bf16x8 whA, whB, wlA, wlB;
#pragma unroll
  for (int q = 0; q < 8; ++q) {
    const float wA = weight[(kq0 + q) * COUT + l15];
    const float wB = weight[(kq0 + q) * COUT + 16 + l15];
    const unsigned uA = __float_as_uint(wA), uB = __float_as_uint(wB);
    const float hA = __uint_as_float(uA & 0xffff0000u);
    const float hB = __uint_as_float(uB & 0xffff0000u);
    whA[q] = (short)(uA >> 16);
    whB[q] = (short)(uB >> 16);
    wlA[q] = (short)(__float_as_uint(wA - hA) >> 16);
    wlB[q] = (short)(__float_as_uint(wB - hB) >> 16);
  }

  asm volatile("s_waitcnt vmcnt(0)" ::: "memory");
  __syncthreads();

#pragma unroll
  for (int t = 0; t < 2; ++t) {
    const int s   = (wv << 1) + t;   // subtile 0..7 (16 j each)
    const int j0s = j0 + (s << 4);

    // Fragment read with the same XOR swizzle: 2-way banks max.
    float xv[8];
#pragma unroll
    for (int q = 0; q < 8; ++q)
      xv[q] = xs[((kq0 + q) << 7) + (((s << 4) + l15) ^ (grp << 4))];

    // hi/lo split: xh = round-half-up bf16, xl = trunc bf16 of residual.
    bf16x8 xh, xl;
#pragma unroll
    for (int q = 0; q < 8; ++q) {
      const unsigned ur = __float_as_uint(xv[q]) + 0x8000u;
      const float hf = __uint_as_float(ur & 0xffff0000u);
      xh[q] = (short)(ur >> 16);
      xl[q] = (short)(__float_as_uint(xv[q] - hf) >> 16);
    }

    // Swapped operands: D = mfma(w, x) -> lane holds j=l15, c=grp*4+reg.
    f32x4 d0 = {0.f, 0.f, 0.f, 0.f}, d1 = {0.f, 0.f, 0.f, 0.f};
    d0 = __builtin_amdgcn_mfma_f32_16x16x32_bf16(whA, xh, d0, 0, 0, 0);
    d0 = __builtin_amdgcn_mfma_f32_16x16x32_bf16(wlA, xh, d0, 0, 0, 0);
    d0 = __builtin_amdgcn_mfma_f32_16x16x32_bf16(whA, xl, d0, 0, 0, 0);
    d1 = __builtin_amdgcn_mfma_f32_16x16x32_bf16(whB, xh, d1, 0, 0, 0);
    d1 = __builtin_amdgcn_mfma_f32_16x16x32_bf16(wlB, xh, d1, 0, 0, 0);
    d1 = __builtin_amdgcn_mfma_f32_16x16x32_bf16(whB, xl, d1, 0, 0, 0);

    // Pack 4 bf16 (RNE) -> one 8B store per frag.
    __hip_bfloat162 p00 = __float22bfloat162_rn(make_float2(d0[0], d0[1]));
    __hip_bfloat162 p01 = __float22bfloat162_rn(make_float2(d0[2], d0[3]));
    __hip_bfloat162 p10 = __float22bfloat162_rn(make_float2(d1[0], d1[1]));
    __hip_bfloat162 p11 = __float22bfloat162_rn(make_float2(d1[2], d1[3]));

    unsigned short* row = zT + ((((size_t)(n << 14)) + j0s + l15) << 5);
    const int cq = grp << 2;  // c-quad base: 0,4,8,12
    *(uint2*)(row + cq)      = make_uint2(*(unsigned*)&p00, *(unsigned*)&p01);
    *(uint2*)(row + 16 + cq) = make_uint2(*(unsigned*)&p10, *(unsigned*)&p11);
  }
}

// ---------------------------------------------------------------------------
// Kernel 2: gather-pool + bias, branch-free (UNCHANGED from R12).
//   out[n][c][o] = bias[c][o] + sum_{m<deg[o]} zT[n][A[o][m]][c]
// ---------------------------------------------------------------------------
__global__ __launch_bounds__(256) void gather_pool_kernel(
    const unsigned* __restrict__ zT,  // bf16x2 words, [n][j][c/2]
    const int* __restrict__ A,
    const float* __restrict__ mask,
    const float* __restrict__ bias,
    float* __restrict__ out) {
  __shared__ int   aIdx[64 * MD];    // 4 KB
  __shared__ int   degS[64];
  __shared__ float otile[COUT][65];  // (c+o)%32 banks: conflict-free

  const int L    = blockIdx.x;
  const int xcd  = L & 7;
  const int slot = L >> 3;                 // 0..255
  const int n    = xcd * 4 + (slot >> 6);  // 4 n per xcd
  const int o0   = (slot & 63) * 64;

  const int tid = threadIdx.x;

  ((int4*)aIdx)[tid] = ((const int4*)(A + o0 * MD))[tid];

  if (tid < 64) {
    const float4* mrow = (const float4*)(mask + (size_t)(o0 + tid) * MD);
    float s = 0.f;
#pragma unroll
    for (int q = 0; q < 4; ++q) {
      float4 v = mrow[q];
      s += v.x + v.y + v.z + v.w;
    }
    degS[tid] = (int)(s + 0.5f);
  }
  __syncthreads();

  const int l16 = tid & 15;  // channel-pair index
  const int grp = tid >> 4;  // 0..15: group owns o = o0 + grp*4 + k

  const unsigned* zn = zT + (((size_t)n) << 18);  // zT[n]: 16384*16 words

  float2 acc[4];
  int    deg[4];
#pragma unroll
  for (int k = 0; k < 4; ++k) {
    acc[k] = make_float2(0.f, 0.f);
    deg[k] = degS[grp * 4 + k];
  }

#define PROC(K, IDX, M)                                      \
  {                                                          \
    const bool on = (M) < deg[K];                            \
    const int  ie = on ? (IDX) : 0;                          \
    const unsigned w = zn[ie * 16 + l16];                    \
    const float f = on ? 1.f : 0.f;                          \
    acc[K].x += f * __uint_as_float(w << 16);                \
    acc[K].y += f * __uint_as_float(w & 0xffff0000u);        \
  }

#pragma unroll
  for (int mq = 0; mq < 4; ++mq) {
    int4 idq[4];
#pragma unroll
    for (int k = 0; k < 4; ++k)
      idq[k] = *(const int4*)&aIdx[(grp * 4 + k) * MD + (mq << 2)];
    const int mb = mq << 2;
#pragma unroll
    for (int k = 0; k < 4; ++k) {
      PROC(k, idq[k].x, mb + 0)
      PROC(k, idq[k].y, mb + 1)
      PROC(k, idq[k].z, mb + 2)
      PROC(k, idq[k].w, mb + 3)
    }
  }
#undef PROC

#pragma unroll
  for (int k = 0; k < 4; ++k) {
    const int o = grp * 4 + k;
    otile[2 * l16][o]     = acc[k].x;
    otile[2 * l16 + 1][o] = acc[k].y;
  }
  __syncthreads();

  const int ol = tid & 63;
  const int cg = (tid >> 6) * 8;
#pragma unroll
  for (int jj = 0; jj < 8; ++jj) {
    const int cc = cg + jj;
    out[((size_t)(n * COUT + cc)) * ON + o0 + ol] =
        otile[cc][ol] + bias[cc * ON + o0 + ol];
  }
}

// ---------------------------------------------------------------------------
// Fallback (ws too small): pool directly from x (strided gather), then mix.
// ---------------------------------------------------------------------------
__global__ __launch_bounds__(256) void fused_direct_kernel(
    const float* __restrict__ x,
    const int* __restrict__ A,
    const float* __restrict__ mask,
    const float* __restrict__ weight,
    const float* __restrict__ bias,
    float* __restrict__ out) {
  __shared__ float pooled[64][33];
  __shared__ float wl[CIN * COUT];

  const int n  = blockIdx.y;
  const int o0 = blockIdx.x * 64;
  const int tid = threadIdx.x;

  for (int k = tid; k < CIN * COUT; k += 256) wl[k] = weight[k];

  const int c = tid & 31;
  const int g = tid >> 5;
  for (int oo = g; oo < 64; oo += 8) {
    const int o = o0 + oo;
    float acc = 0.f;
#pragma unroll
    for (int m = 0; m < MD; ++m) {
      const float f = mask[o * MD + m];
      if (f == 0.f) break;
      const int idx = A[o * MD + m];
      acc += f * x[(((size_t)(n * CIN + c)) << 14) + idx];
    }
    pooled[oo][c] = acc;
  }
  __syncthreads();

  const int ol = tid & 63;
  const int cg = (tid >> 6) * 8;
  float y[8];
#pragma unroll
  for (int jj = 0; jj < 8; ++jj) y[jj] = bias[(cg + jj) * ON + o0 + ol];
  for (int i = 0; i < CIN; ++i) {
    const float p = pooled[ol][i];
#pragma unroll
    for (int jj = 0; jj < 8; ++jj) y[jj] += p * wl[i * 32 + cg + jj];
  }
#pragma unroll
  for (int jj = 0; jj < 8; ++jj)
    out[((size_t)(n * COUT + cg + jj)) * ON + o0 + ol] = y[jj];
}

extern "C" void kernel_launch(void* const* d_in, const int* in_sizes, int n_in,
                              void* d_out, int out_size, void* d_ws, size_t ws_size,
                              hipStream_t stream) {
  const float* x      = (const float*)d_in[0];
  const int*   A      = (const int*)d_in[1];
  const float* mask   = (const float*)d_in[2];
  const float* weight = (const float*)d_in[3];
  const float* bias   = (const float*)d_in[4];
  float* out = (float*)d_out;

  const size_t need = (size_t)NB * INN_ * COUT * sizeof(unsigned short);  // 32MB
  if (ws_size >= need) {
    unsigned short* zT = (unsigned short*)d_ws;
    premix_mfma_kernel<<<4096, 256, 0, stream>>>(x, weight, zT);
    gather_pool_kernel<<<2048, 256, 0, stream>>>((const unsigned*)zT, A, mask,
                                                 bias, out);
  } else {
    fused_direct_kernel<<<dim3(ON / 64, NB), 256, 0, stream>>>(
        x, A, mask, weight, bias, out);
  }
}

// Round 17
// 35.309 us; speedup vs baseline: 1.0017x; 1.0017x over previous
//
#include <hip/hip_runtime.h>
#include <hip/hip_bf16.h>

// Problem constants (fixed by reference)
#define NB   32      // N  (batch)
#define CIN  32      // INC
#define COUT 32      // OUTC
#define INN_ 16384   // INN
#define ON   4096    // OUTN
#define MD   16      // MAXD

typedef __attribute__((ext_vector_type(8))) short bf16x8;  // 8 bf16 = 4 VGPR
typedef __attribute__((ext_vector_type(4))) float f32x4;

typedef const __attribute__((address_space(1))) void* gas_ptr;
typedef __attribute__((address_space(3))) void* las_ptr;

// ---------------------------------------------------------------------------
// Kernel 1: premix via MFMA (UNCHANGED from R16: async global_load_lds,
// XCD-aligned n mapping).  zT[n][j][c] = sum_i x[n][i][j]*w[i][c], bf16.
// ---------------------------------------------------------------------------
__global__ __launch_bounds__(256) void premix_mfma_kernel(
    const float* __restrict__ x,
    const float* __restrict__ weight,
    unsigned short* __restrict__ zT) {
  __shared__ float xs[CIN * 128];  // linear, 16 KB

  const int tid  = threadIdx.x;
  const int lane = tid & 63;
  const int wv   = tid >> 6;
  const int l15  = lane & 15;
  const int grp  = lane >> 4;   // 0..3
  const int kq0  = grp << 3;    // i-base 0,8,16,24

  const int L    = blockIdx.x;
  const int xcd  = L & 7;
  const int slot = L >> 3;                  // 0..511
  const int n    = xcd * 4 + (slot >> 7);   // 4 n per xcd
  const int j0   = (slot & 127) << 7;       // 128-j tile

  const float* xgbase = x + (((size_t)n * CIN) << 14) + j0;
#pragma unroll
  for (int r = 0; r < 4; ++r) {
    const int c   = (r << 2) + wv;
    const int row = (c << 1) + (lane >> 5);
    const int off = ((lane & 31) << 2) ^ ((row & 24) << 1);
    const float* gsrc = xgbase + ((size_t)row << 14) + off;
    __builtin_amdgcn_global_load_lds((gas_ptr)(const void*)gsrc,
                                     (las_ptr)(void*)&xs[c << 8], 16, 0, 0);
  }

  bf16x8 whA, whB, wlA, wlB;
#pragma unroll
  for (int q = 0; q < 8; ++q) {
    const float wA = weight[(kq0 + q) * COUT + l15];
    const float wB = weight[(kq0 + q) * COUT + 16 + l15];
    const unsigned uA = __float_as_uint(wA), uB = __float_as_uint(wB);
    const float hA = __uint_as_float(uA & 0xffff0000u);
    const float hB = __uint_as_float(uB & 0xffff0000u);
    whA[q] = (short)(uA >> 16);
    whB[q] = (short)(uB >> 16);
    wlA[q] = (short)(__float_as_uint(wA - hA) >> 16);
    wlB[q] = (short)(__float_as_uint(wB - hB) >> 16);
  }

  asm volatile("s_waitcnt vmcnt(0)" ::: "memory");
  __syncthreads();

#pragma unroll
  for (int t = 0; t < 2; ++t) {
    const int s   = (wv << 1) + t;
    const int j0s = j0 + (s << 4);

    float xv[8];
#pragma unroll
    for (int q = 0; q < 8; ++q)
      xv[q] = xs[((kq0 + q) << 7) + (((s << 4) + l15) ^ (grp << 4))];

    bf16x8 xh, xl;
#pragma unroll
    for (int q = 0; q < 8; ++q) {
      const unsigned ur = __float_as_uint(xv[q]) + 0x8000u;
      const float hf = __uint_as_float(ur & 0xffff0000u);
      xh[q] = (short)(ur >> 16);
      xl[q] = (short)(__float_as_uint(xv[q] - hf) >> 16);
    }

    f32x4 d0 = {0.f, 0.f, 0.f, 0.f}, d1 = {0.f, 0.f, 0.f, 0.f};
    d0 = __builtin_amdgcn_mfma_f32_16x16x32_bf16(whA, xh, d0, 0, 0, 0);
    d0 = __builtin_amdgcn_mfma_f32_16x16x32_bf16(wlA, xh, d0, 0, 0, 0);
    d0 = __builtin_amdgcn_mfma_f32_16x16x32_bf16(whA, xl, d0, 0, 0, 0);
    d1 = __builtin_amdgcn_mfma_f32_16x16x32_bf16(whB, xh, d1, 0, 0, 0);
    d1 = __builtin_amdgcn_mfma_f32_16x16x32_bf16(wlB, xh, d1, 0, 0, 0);
    d1 = __builtin_amdgcn_mfma_f32_16x16x32_bf16(whB, xl, d1, 0, 0, 0);

    __hip_bfloat162 p00 = __float22bfloat162_rn(make_float2(d0[0], d0[1]));
    __hip_bfloat162 p01 = __float22bfloat162_rn(make_float2(d0[2], d0[3]));
    __hip_bfloat162 p10 = __float22bfloat162_rn(make_float2(d1[0], d1[1]));
    __hip_bfloat162 p11 = __float22bfloat162_rn(make_float2(d1[2], d1[3]));

    unsigned short* row = zT + ((((size_t)(n << 14)) + j0s + l15) << 5);
    const int cq = grp << 2;
    *(uint2*)(row + cq)      = make_uint2(*(unsigned*)&p00, *(unsigned*)&p01);
    *(uint2*)(row + 16 + cq) = make_uint2(*(unsigned*)&p10, *(unsigned*)&p11);
  }
}

// ---------------------------------------------------------------------------
// Kernel 2: gather-pool + bias, branch-free + DEG-SORTED wave-tight bounds.
// Counting-sort the 64 o's by degree; wave w processes sorted ranks
// [16w,16w+16) -> wave-uniform m-loop bound = its max deg (avg ~{5,9,13,16}
// vs 16 always: ~28% fewer gather instrs). otile indexed by ORIGINAL o ->
// writes stay coalesced; per-o summation order unchanged (bitwise-identical).
// ---------------------------------------------------------------------------
__global__ __launch_bounds__(256) void gather_pool_kernel(
    const unsigned* __restrict__ zT,  // bf16x2 words, [n][j][c/2]
    const int* __restrict__ A,
    const float* __restrict__ mask,
    const float* __restrict__ bias,
    float* __restrict__ out) {
  __shared__ int   aIdx[64 * MD];    // 4 KB
  __shared__ int   deg64[64];
  __shared__ int   sortIdx[64];
  __shared__ int   bucket[17];
  __shared__ int   wmaxS[4];
  __shared__ float otile[COUT][65];  // (c+o)%32 banks: conflict-free

  const int L    = blockIdx.x;
  const int xcd  = L & 7;
  const int slot = L >> 3;                 // 0..255
  const int n    = xcd * 4 + (slot >> 6);  // 4 n per xcd
  const int o0   = (slot & 63) * 64;

  const int tid = threadIdx.x;

  // Stage A rows: 1024 ints, one int4 per thread, coalesced.
  ((int4*)aIdx)[tid] = ((const int4*)(A + o0 * MD))[tid];

  if (tid < 17) bucket[tid] = 0;
  __syncthreads();

  // Degrees: mask rows are exactly {1.0 x deg, 0.0 ...}.
  if (tid < 64) {
    const float4* mrow = (const float4*)(mask + (size_t)(o0 + tid) * MD);
    float s = 0.f;
#pragma unroll
    for (int q = 0; q < 4; ++q) {
      float4 v = mrow[q];
      s += v.x + v.y + v.z + v.w;
    }
    const int d = (int)(s + 0.5f);
    deg64[tid] = d;
    atomicAdd(&bucket[d], 1);
  }
  __syncthreads();

  if (tid == 0) {  // exclusive prefix over deg 1..16
    int s = 0;
#pragma unroll
    for (int d = 1; d <= 16; ++d) {
      const int c = bucket[d];
      bucket[d] = s;
      s += c;
    }
  }
  __syncthreads();

  if (tid < 64) {
    const int pos = atomicAdd(&bucket[deg64[tid]], 1);
    sortIdx[pos] = tid;  // ascending by deg (stable-ish; order in bucket free)
  }
  __syncthreads();

  if (tid < 4) wmaxS[tid] = deg64[sortIdx[16 * tid + 15]];
  __syncthreads();

  const int l16  = tid & 15;  // channel-pair index
  const int grp  = tid >> 4;  // 0..15
  const int wvid = tid >> 6;  // 0..3

  const unsigned* zn = zT + (((size_t)n) << 18);  // zT[n]: 16384*16 words

  int   oL[4], dg[4];
  float2 acc[4];
#pragma unroll
  for (int k = 0; k < 4; ++k) {
    oL[k]  = sortIdx[grp * 4 + k];   // original o offset (0..63)
    dg[k]  = deg64[oL[k]];
    acc[k] = make_float2(0.f, 0.f);
  }

  const int wb = wmaxS[wvid];        // wave-uniform bound
  const int nq = (wb + 1) >> 1;      // chunks of 2

#define PROC(K, IDX, M)                                      \
  {                                                          \
    const bool on = (M) < dg[K];                             \
    const int  ie = on ? (IDX) : 0;                          \
    const unsigned w = zn[ie * 16 + l16];                    \
    const float f = on ? 1.f : 0.f;                          \
    acc[K].x += f * __uint_as_float(w << 16);                \
    acc[K].y += f * __uint_as_float(w & 0xffff0000u);        \
  }

  for (int mq = 0; mq < nq; ++mq) {
    const int mb = mq << 1;
    int2 idq[4];
#pragma unroll
    for (int k = 0; k < 4; ++k)
      idq[k] = *(const int2*)&aIdx[oL[k] * MD + mb];
#pragma unroll
    for (int k = 0; k < 4; ++k) {
      PROC(k, idq[k].x, mb + 0)
      PROC(k, idq[k].y, mb + 1)
    }
  }
#undef PROC

#pragma unroll
  for (int k = 0; k < 4; ++k) {
    const int o = oL[k];
    otile[2 * l16][o]     = acc[k].x;
    otile[2 * l16 + 1][o] = acc[k].y;
  }
  __syncthreads();

  const int ol = tid & 63;
  const int cg = (tid >> 6) * 8;
#pragma unroll
  for (int jj = 0; jj < 8; ++jj) {
    const int cc = cg + jj;
    out[((size_t)(n * COUT + cc)) * ON + o0 + ol] =
        otile[cc][ol] + bias[cc * ON + o0 + ol];
  }
}

// ---------------------------------------------------------------------------
// Fallback (ws too small): pool directly from x (strided gather), then mix.
// ---------------------------------------------------------------------------
__global__ __launch_bounds__(256) void fused_direct_kernel(
    const float* __restrict__ x,
    const int* __restrict__ A,
    const float* __restrict__ mask,
    const float* __restrict__ weight,
    const float* __restrict__ bias,
    float* __restrict__ out) {
  __shared__ float pooled[64][33];
  __shared__ float wl[CIN * COUT];

  const int n  = blockIdx.y;
  const int o0 = blockIdx.x * 64;
  const int tid = threadIdx.x;

  for (int k = tid; k < CIN * COUT; k += 256) wl[k] = weight[k];

  const int c = tid & 31;
  const int g = tid >> 5;
  for (int oo = g; oo < 64; oo += 8) {
    const int o = o0 + oo;
    float acc = 0.f;
#pragma unroll
    for (int m = 0; m < MD; ++m) {
      const float f = mask[o * MD + m];
      if (f == 0.f) break;
      const int idx = A[o * MD + m];
      acc += f * x[(((size_t)(n * CIN + c)) << 14) + idx];
    }
    pooled[oo][c] = acc;
  }
  __syncthreads();

  const int ol = tid & 63;
  const int cg = (tid >> 6) * 8;
  float y[8];
#pragma unroll
  for (int jj = 0; jj < 8; ++jj) y[jj] = bias[(cg + jj) * ON + o0 + ol];
  for (int i = 0; i < CIN; ++i) {
    const float p = pooled[ol][i];
#pragma unroll
    for (int jj = 0; jj < 8; ++jj) y[jj] += p * wl[i * 32 + cg + jj];
  }
#pragma unroll
  for (int jj = 0; jj < 8; ++jj)
    out[((size_t)(n * COUT + cg + jj)) * ON + o0 + ol] = y[jj];
}

extern "C" void kernel_launch(void* const* d_in, const int* in_sizes, int n_in,
                              void* d_out, int out_size, void* d_ws, size_t ws_size,
                              hipStream_t stream) {
  const float* x      = (const float*)d_in[0];
  const int*   A      = (const int*)d_in[1];
  const float* mask   = (const float*)d_in[2];
  const float* weight = (const float*)d_in[3];
  const float* bias   = (const float*)d_in[4];
  float* out = (float*)d_out;

  const size_t need = (size_t)NB * INN_ * COUT * sizeof(unsigned short);  // 32MB
  if (ws_size >= need) {
    unsigned short* zT = (unsigned short*)d_ws;
    premix_mfma_kernel<<<4096, 256, 0, stream>>>(x, weight, zT);
    gather_pool_kernel<<<2048, 256, 0, stream>>>((const unsigned*)zT, A, mask,
                                                 bias, out);
  } else {
    fused_direct_kernel<<<dim3(ON / 64, NB), 256, 0, stream>>>(
        x, A, mask, weight, bias, out);
  }
}